// Round 10
// baseline (51.207 us; speedup 1.0000x reference)
//
#include <hip/hip_runtime.h>
#include <hip/hip_bf16.h>

// CosSim2D: inputs (32,64,64,64) f32, w (1,576,128) f32, p (128), q (1)
// out (32,64,64,128) f32.
// R10: 2-wave blocks (128 thr), wave = 128 px x 64 n (acc[8][4], m=8).
// B:MFMA ratio 1:8 halves per-CU B-L2 traffic (the R4/R9 co-limiter) to
// ~576 KB/CU. Same 38KB A-tile -> 4 blocks/CU. Fragment-contiguous B,
// fused fp32 norm, barrier-free epilogue.

typedef short bf16x8 __attribute__((ext_vector_type(8)));
typedef float f32x4 __attribute__((ext_vector_type(4)));

__device__ __forceinline__ unsigned short f2bf(float f) {
    union { float f; unsigned int u; } v; v.f = f;
    unsigned int u = v.u;
    unsigned int r = (u + 0x7fffu + ((u >> 16) & 1u)) >> 16;  // RNE
    return (unsigned short)r;
}

// ---- pre-kernel: normalize w columns (fp32), store bf16 fragment-contiguous:
// wn2[((tap*2 + kc)*128 + n)*32 + koff] = w_hat[k = tap*64 + kc*32 + koff][n]
__global__ void prep_w_kernel(const float* __restrict__ w,
                              unsigned short* __restrict__ wn2) {
    const int n = blockIdx.x;
    const int lane = threadIdx.x;
    float vals[9];
    float s = 0.f;
#pragma unroll
    for (int i = 0; i < 9; ++i) {
        float v = w[(i * 64 + lane) * 128 + n];
        vals[i] = v;
        s += v * v;
    }
#pragma unroll
    for (int off = 1; off < 64; off <<= 1) s += __shfl_xor(s, off);
    const float inv = 1.0f / sqrtf(fmaxf(s, 1e-12f));
    const int kc = lane >> 5, koff = lane & 31;
#pragma unroll
    for (int i = 0; i < 9; ++i)
        wn2[((i * 2 + kc) * 128 + n) * 32 + koff] = f2bf(vals[i] * inv);
}

// ---- main: block = 128 threads (2 waves) = (image b, rows y0,y0+1);
// wave wv owns ALL 128 px x 64-n half wv.
__global__ __launch_bounds__(128, 2) void cossim_main(
    const float* __restrict__ in, const unsigned short* __restrict__ wn,
    const float* __restrict__ p, const float* __restrict__ q,
    float* __restrict__ out) {
    // A: [4 rows][66 cols (zero-pad 0,65)][72 ch (64 + 16B pad)] bf16 = 38016 B
    __shared__ unsigned short A[4 * 66 * 72];
    __shared__ float rcsum[256];   // per-(row,col) fp32 square-sums
    __shared__ float xni[128];     // per-pixel 1/(||x||+q_eff)
    __shared__ float pfs[128];     // exp(p/P_SCALE)

    const int tid = (int)threadIdx.x;
    // bijective XCD swizzle: 1024 blocks, 8 XCDs, 128 consecutive l per XCD
    const int l = ((int)blockIdx.x & 7) * 128 + ((int)blockIdx.x >> 3);
    const int b = l >> 5, y0 = (l & 31) * 2;

    pfs[tid] = expf(p[tid] * 0.2f);   // all 128 threads

    // ---- stage 4 input rows (y0-1 .. y0+2): 2 (row,col) units per thread
#pragma unroll
    for (int u2 = 0; u2 < 2; ++u2) {
        const int u = tid + u2 * 128;
        const int r = u >> 6;          // staged row 0..3
        const int col = u & 63;
        const int row = y0 + r - 1;
        unsigned short* dst = &A[(r * 66 + col + 1) * 72];
        float s = 0.f;
        if ((unsigned)row < 64u) {
            const float4* src = reinterpret_cast<const float4*>(
                in + (size_t)b * 262144 + row * 4096 + col * 64);
#pragma unroll
            for (int it = 0; it < 8; ++it) {
                float4 v0 = src[2 * it];
                float4 v1 = src[2 * it + 1];
                s += v0.x * v0.x + v0.y * v0.y + v0.z * v0.z + v0.w * v0.w;
                s += v1.x * v1.x + v1.y * v1.y + v1.z * v1.z + v1.w * v1.w;
                union { float f; unsigned u; } ux, uy, uz, uw;
                uint4 pk;
                ux.f = v0.x; uy.f = v0.y; uz.f = v0.z; uw.f = v0.w;
                pk.x = __builtin_amdgcn_perm(uy.u + 0x8000u, ux.u + 0x8000u, 0x07060302u);
                pk.y = __builtin_amdgcn_perm(uw.u + 0x8000u, uz.u + 0x8000u, 0x07060302u);
                ux.f = v1.x; uy.f = v1.y; uz.f = v1.z; uw.f = v1.w;
                pk.z = __builtin_amdgcn_perm(uy.u + 0x8000u, ux.u + 0x8000u, 0x07060302u);
                pk.w = __builtin_amdgcn_perm(uw.u + 0x8000u, uz.u + 0x8000u, 0x07060302u);
                *reinterpret_cast<uint4*>(dst + it * 8) = pk;
            }
        } else {
            uint4 z; z.x = z.y = z.z = z.w = 0u;
#pragma unroll
            for (int it = 0; it < 8; ++it)
                *reinterpret_cast<uint4*>(dst + it * 8) = z;
        }
        rcsum[u] = s;
    }
    if (tid < 64) {  // zero border cols 0 and 65, all 4 rows
        const int r = tid >> 4, side = (tid >> 3) & 1, ch = (tid & 7) * 8;
        uint4 z; z.x = z.y = z.z = z.w = 0u;
        *reinterpret_cast<uint4*>(&A[(r * 66 + side * 65) * 72 + ch]) = z;
    }
    __syncthreads();

    // ---- per-pixel 1/(||x||+q_eff); 128 threads = 128 pixels
    {
        const int ry = tid >> 6, x = tid & 63;
        const float qe = expf(q[0] * (-1.0f / 0.3f));
        float s = 0.f;
#pragma unroll
        for (int dy = 0; dy < 3; ++dy) {
            const float* rs = &rcsum[(ry + dy) * 64];
            if (x > 0) s += rs[x - 1];
            s += rs[x];
            if (x < 63) s += rs[x + 1];
        }
        xni[tid] = 1.0f / (sqrtf(fmaxf(s, 1e-12f)) + qe);
    }
    __syncthreads();   // xni/pfs ready -> epilogue needs NO barrier

    // ---- MFMA loop: wave wv covers 128 px x n-half wv; acc[8][4]
    const int wv = tid >> 6, lane = tid & 63;
    const int lr = lane & 15, lg = lane >> 4;
    f32x4 acc[8][4] = {};
    const unsigned short* wB = wn + (wv * 64 + lr) * 32 + lg * 8;

    bf16x8 bc0 = *reinterpret_cast<const bf16x8*>(wB);
    bf16x8 bc1 = *reinterpret_cast<const bf16x8*>(wB + 512);
    bf16x8 bc2 = *reinterpret_cast<const bf16x8*>(wB + 1024);
    bf16x8 bc3 = *reinterpret_cast<const bf16x8*>(wB + 1536);

#pragma unroll
    for (int s = 0; s < 18; ++s) {
        bf16x8 bn0, bn1, bn2, bn3;
        if (s + 1 < 18) {
            const unsigned short* wt = wB + (s + 1) * 4096;
            bn0 = *reinterpret_cast<const bf16x8*>(wt);
            bn1 = *reinterpret_cast<const bf16x8*>(wt + 512);
            bn2 = *reinterpret_cast<const bf16x8*>(wt + 1024);
            bn3 = *reinterpret_cast<const bf16x8*>(wt + 1536);
        }
        const int dy = s / 6, dx = (s >> 1) % 3, kc = s & 1;
#pragma unroll
        for (int mf = 0; mf < 8; ++mf) {
            // px group mf: row (mf>>2), cols (mf&3)*16 + lr + dx
            const unsigned short* ap =
                &A[(((mf >> 2) + dy) * 66 + (mf & 3) * 16 + lr + dx) * 72
                   + kc * 32 + lg * 8];
            bf16x8 av = *reinterpret_cast<const bf16x8*>(ap);
            acc[mf][0] = __builtin_amdgcn_mfma_f32_16x16x32_bf16(av, bc0, acc[mf][0], 0, 0, 0);
            acc[mf][1] = __builtin_amdgcn_mfma_f32_16x16x32_bf16(av, bc1, acc[mf][1], 0, 0, 0);
            acc[mf][2] = __builtin_amdgcn_mfma_f32_16x16x32_bf16(av, bc2, acc[mf][2], 0, 0, 0);
            acc[mf][3] = __builtin_amdgcn_mfma_f32_16x16x32_bf16(av, bc3, acc[mf][3], 0, 0, 0);
        }
        bc0 = bn0; bc1 = bn1; bc2 = bn2; bc3 = bn3;
    }

    // ---- epilogue (barrier-free): sim = acc*xni; out = sign*(|sim|+eps)^p
    const float* pf = &pfs[wv * 64];
#pragma unroll
    for (int mf = 0; mf < 8; ++mf) {
        float* orow = out + ((size_t)(b * 64 + y0 + (mf >> 2)) * 64) * 128 + wv * 64;
#pragma unroll
        for (int i = 0; i < 4; ++i) {
            const int pix = mf * 16 + lg * 4 + i;          // 0..127
            const int px = pix & 63;                       // col in row
            const float xn = xni[pix];
#pragma unroll
            for (int nf = 0; nf < 4; ++nf) {
                const int n = nf * 16 + lr;
                float sim = acc[mf][nf][i] * xn;
                float aa = fabsf(sim) + 1e-6f;
                float r = exp2f(pf[n] * log2f(aa));
                orow[(size_t)px * 128 + n] = copysignf(r, sim);
            }
        }
    }
}

extern "C" void kernel_launch(void* const* d_in, const int* in_sizes, int n_in,
                              void* d_out, int out_size, void* d_ws, size_t ws_size,
                              hipStream_t stream) {
    (void)in_sizes; (void)n_in; (void)out_size; (void)ws_size;
    const float* in = (const float*)d_in[0];
    const float* w  = (const float*)d_in[1];
    const float* p  = (const float*)d_in[2];
    const float* q  = (const float*)d_in[3];
    float* out = (float*)d_out;
    unsigned short* wn = (unsigned short*)d_ws;  // 18*128*32 bf16 = 147456 B

    prep_w_kernel<<<128, 64, 0, stream>>>(w, wn);
    cossim_main<<<1024, 128, 0, stream>>>(in, wn, p, q, out);
}

// Round 11
// 48.088 us; speedup vs baseline: 1.0649x; 1.0649x over previous
//
#include <hip/hip_runtime.h>
#include <hip/hip_bf16.h>

// CosSim2D: inputs (32,64,64,64) f32, w (1,576,128) f32, p (128), q (1)
// out (32,64,64,128) f32.
// R11 = R10 compute (2-wave blocks, wave = 128px x 64n, acc[8][4], B:MFMA 1:8)
//     + R8 epilogue (LDS-transpose to px-major float4 full-line stores).
// A-tile LDS reused as OB[128][68] f32 after MFMA; two serialized n-half
// passes keep LDS at 40KB -> 4 blocks/CU.

typedef short bf16x8 __attribute__((ext_vector_type(8)));
typedef float f32x4 __attribute__((ext_vector_type(4)));

__device__ __forceinline__ unsigned short f2bf(float f) {
    union { float f; unsigned int u; } v; v.f = f;
    unsigned int u = v.u;
    unsigned int r = (u + 0x7fffu + ((u >> 16) & 1u)) >> 16;  // RNE
    return (unsigned short)r;
}

// ---- pre-kernel: normalize w columns (fp32), store bf16 fragment-contiguous:
// wn2[((tap*2 + kc)*128 + n)*32 + koff] = w_hat[k = tap*64 + kc*32 + koff][n]
__global__ void prep_w_kernel(const float* __restrict__ w,
                              unsigned short* __restrict__ wn2) {
    const int n = blockIdx.x;
    const int lane = threadIdx.x;
    float vals[9];
    float s = 0.f;
#pragma unroll
    for (int i = 0; i < 9; ++i) {
        float v = w[(i * 64 + lane) * 128 + n];
        vals[i] = v;
        s += v * v;
    }
#pragma unroll
    for (int off = 1; off < 64; off <<= 1) s += __shfl_xor(s, off);
    const float inv = 1.0f / sqrtf(fmaxf(s, 1e-12f));
    const int kc = lane >> 5, koff = lane & 31;
#pragma unroll
    for (int i = 0; i < 9; ++i)
        wn2[((i * 2 + kc) * 128 + n) * 32 + koff] = f2bf(vals[i] * inv);
}

#define OBLD 68   // OB row stride in floats (16B aligned, bank-skewed)

// ---- main: block = 128 threads (2 waves) = (image b, rows y0,y0+1);
// wave wv computes ALL 128 px for n-half wv.
__global__ __launch_bounds__(128, 2) void cossim_main(
    const float* __restrict__ in, const unsigned short* __restrict__ wn,
    const float* __restrict__ p, const float* __restrict__ q,
    float* __restrict__ out) {
    // A: [4 rows][66 cols][72 ch] bf16 = 38016 B; reused as OB[128][68] f32
    // (34816 B) for the store transpose after MFMA.
    __shared__ __align__(16) unsigned char smemRaw[4 * 66 * 72 * 2];
    unsigned short* A = reinterpret_cast<unsigned short*>(smemRaw);
    float* OB = reinterpret_cast<float*>(smemRaw);
    __shared__ float rcsum[256];   // per-(row,col) fp32 square-sums
    __shared__ float xni[128];     // per-pixel 1/(||x||+q_eff)
    __shared__ float pfs[128];     // exp(p/P_SCALE)

    const int tid = (int)threadIdx.x;
    // bijective XCD swizzle: 1024 blocks, 8 XCDs, 128 consecutive l per XCD
    const int l = ((int)blockIdx.x & 7) * 128 + ((int)blockIdx.x >> 3);
    const int b = l >> 5, y0 = (l & 31) * 2;

    pfs[tid] = expf(p[tid] * 0.2f);   // all 128 threads

    // ---- stage 4 input rows (y0-1 .. y0+2): 2 (row,col) units per thread
#pragma unroll
    for (int u2 = 0; u2 < 2; ++u2) {
        const int u = tid + u2 * 128;
        const int r = u >> 6;          // staged row 0..3
        const int col = u & 63;
        const int row = y0 + r - 1;
        unsigned short* dst = &A[(r * 66 + col + 1) * 72];
        float s = 0.f;
        if ((unsigned)row < 64u) {
            const float4* src = reinterpret_cast<const float4*>(
                in + (size_t)b * 262144 + row * 4096 + col * 64);
#pragma unroll
            for (int it = 0; it < 8; ++it) {
                float4 v0 = src[2 * it];
                float4 v1 = src[2 * it + 1];
                s += v0.x * v0.x + v0.y * v0.y + v0.z * v0.z + v0.w * v0.w;
                s += v1.x * v1.x + v1.y * v1.y + v1.z * v1.z + v1.w * v1.w;
                union { float f; unsigned u; } ux, uy, uz, uw;
                uint4 pk;
                ux.f = v0.x; uy.f = v0.y; uz.f = v0.z; uw.f = v0.w;
                pk.x = __builtin_amdgcn_perm(uy.u + 0x8000u, ux.u + 0x8000u, 0x07060302u);
                pk.y = __builtin_amdgcn_perm(uw.u + 0x8000u, uz.u + 0x8000u, 0x07060302u);
                ux.f = v1.x; uy.f = v1.y; uz.f = v1.z; uw.f = v1.w;
                pk.z = __builtin_amdgcn_perm(uy.u + 0x8000u, ux.u + 0x8000u, 0x07060302u);
                pk.w = __builtin_amdgcn_perm(uw.u + 0x8000u, uz.u + 0x8000u, 0x07060302u);
                *reinterpret_cast<uint4*>(dst + it * 8) = pk;
            }
        } else {
            uint4 z; z.x = z.y = z.z = z.w = 0u;
#pragma unroll
            for (int it = 0; it < 8; ++it)
                *reinterpret_cast<uint4*>(dst + it * 8) = z;
        }
        rcsum[u] = s;
    }
    if (tid < 64) {  // zero border cols 0 and 65, all 4 rows
        const int r = tid >> 4, side = (tid >> 3) & 1, ch = (tid & 7) * 8;
        uint4 z; z.x = z.y = z.z = z.w = 0u;
        *reinterpret_cast<uint4*>(&A[(r * 66 + side * 65) * 72 + ch]) = z;
    }
    __syncthreads();

    // ---- per-pixel 1/(||x||+q_eff); 128 threads = 128 pixels
    {
        const int ry = tid >> 6, x = tid & 63;
        const float qe = expf(q[0] * (-1.0f / 0.3f));
        float s = 0.f;
#pragma unroll
        for (int dy = 0; dy < 3; ++dy) {
            const float* rs = &rcsum[(ry + dy) * 64];
            if (x > 0) s += rs[x - 1];
            s += rs[x];
            if (x < 63) s += rs[x + 1];
        }
        xni[tid] = 1.0f / (sqrtf(fmaxf(s, 1e-12f)) + qe);
    }
    __syncthreads();   // xni/pfs ready

    // ---- MFMA loop: wave wv covers 128 px x n-half wv; acc[8][4]
    const int wv = tid >> 6, lane = tid & 63;
    const int lr = lane & 15, lg = lane >> 4;
    f32x4 acc[8][4] = {};
    const unsigned short* wB = wn + (wv * 64 + lr) * 32 + lg * 8;

    bf16x8 bc0 = *reinterpret_cast<const bf16x8*>(wB);
    bf16x8 bc1 = *reinterpret_cast<const bf16x8*>(wB + 512);
    bf16x8 bc2 = *reinterpret_cast<const bf16x8*>(wB + 1024);
    bf16x8 bc3 = *reinterpret_cast<const bf16x8*>(wB + 1536);

#pragma unroll
    for (int s = 0; s < 18; ++s) {
        bf16x8 bn0, bn1, bn2, bn3;
        if (s + 1 < 18) {
            const unsigned short* wt = wB + (s + 1) * 4096;
            bn0 = *reinterpret_cast<const bf16x8*>(wt);
            bn1 = *reinterpret_cast<const bf16x8*>(wt + 512);
            bn2 = *reinterpret_cast<const bf16x8*>(wt + 1024);
            bn3 = *reinterpret_cast<const bf16x8*>(wt + 1536);
        }
        const int dy = s / 6, dx = (s >> 1) % 3, kc = s & 1;
#pragma unroll
        for (int mf = 0; mf < 8; ++mf) {
            const unsigned short* ap =
                &A[(((mf >> 2) + dy) * 66 + (mf & 3) * 16 + lr + dx) * 72
                   + kc * 32 + lg * 8];
            bf16x8 av = *reinterpret_cast<const bf16x8*>(ap);
            acc[mf][0] = __builtin_amdgcn_mfma_f32_16x16x32_bf16(av, bc0, acc[mf][0], 0, 0, 0);
            acc[mf][1] = __builtin_amdgcn_mfma_f32_16x16x32_bf16(av, bc1, acc[mf][1], 0, 0, 0);
            acc[mf][2] = __builtin_amdgcn_mfma_f32_16x16x32_bf16(av, bc2, acc[mf][2], 0, 0, 0);
            acc[mf][3] = __builtin_amdgcn_mfma_f32_16x16x32_bf16(av, bc3, acc[mf][3], 0, 0, 0);
        }
        bc0 = bn0; bc1 = bn1; bc2 = bn2; bc3 = bn3;
    }
    __syncthreads();   // all A-reads done -> A space reusable as OB

    // ---- epilogue: two serialized n-half passes through OB, float4 stores
    const float* pf = &pfs[wv * 64];
#pragma unroll
    for (int h = 0; h < 2; ++h) {
        if (wv == h) {
#pragma unroll
            for (int mf = 0; mf < 8; ++mf) {
#pragma unroll
                for (int i = 0; i < 4; ++i) {
                    const int pix = mf * 16 + lg * 4 + i;   // 0..127
                    const float xn = xni[pix];
#pragma unroll
                    for (int nf = 0; nf < 4; ++nf) {
                        const int n = nf * 16 + lr;
                        float sim = acc[mf][nf][i] * xn;
                        float aa = fabsf(sim) + 1e-6f;
                        float r = exp2f(pf[n] * log2f(aa));
                        OB[pix * OBLD + n] = copysignf(r, sim);
                    }
                }
            }
        }
        __syncthreads();   // OB half ready
        // both waves copy out: 2048 float4 / 128 thr = 16 each.
        // per wave-instruction: 4 px x 256 contiguous B = complete 128B lines
#pragma unroll
        for (int j = 0; j < 16; ++j) {
            const int f = tid + 128 * j;      // 0..2047
            const int px = f >> 4, c = f & 15;
            float4 v = *reinterpret_cast<const float4*>(&OB[px * OBLD + c * 4]);
            const int row = y0 + (px >> 6), col = px & 63;
            *reinterpret_cast<float4*>(
                out + ((size_t)((b * 64 + row) * 64 + col)) * 128 + h * 64 + c * 4) = v;
        }
        if (h == 0) __syncthreads();   // copy reads done before pass-1 overwrite
    }
}

extern "C" void kernel_launch(void* const* d_in, const int* in_sizes, int n_in,
                              void* d_out, int out_size, void* d_ws, size_t ws_size,
                              hipStream_t stream) {
    (void)in_sizes; (void)n_in; (void)out_size; (void)ws_size;
    const float* in = (const float*)d_in[0];
    const float* w  = (const float*)d_in[1];
    const float* p  = (const float*)d_in[2];
    const float* q  = (const float*)d_in[3];
    float* out = (float*)d_out;
    unsigned short* wn = (unsigned short*)d_ws;  // 18*128*32 bf16 = 147456 B

    prep_w_kernel<<<128, 64, 0, stream>>>(w, wn);
    cossim_main<<<1024, 128, 0, stream>>>(in, wn, p, q, out);
}